// Round 1
// baseline (1836.356 us; speedup 1.0000x reference)
//
#include <hip/hip_runtime.h>
#include <hip/hip_bf16.h>

#define N_NODES 100000
#define N_EDGES 1600000
#define F_IN    128
#define H       256
#define NHID    512
#define NOUT    256
#define G_GR    256

typedef unsigned short u16;

__device__ __forceinline__ float bf2f(u16 u) {
    union { unsigned int i; float f; } v; v.i = ((unsigned int)u) << 16; return v.f;
}
__device__ __forceinline__ u16 f2bf(float f) {
    union { float f; unsigned int i; } v; v.f = f;
    unsigned int x = v.i;
    x += 0x7fffu + ((x >> 16) & 1u);   // round-to-nearest-even
    return (u16)(x >> 16);
}

// ---------------- graph prep ----------------

__global__ void count_deg(const int* __restrict__ dst, int* __restrict__ degc) {
    int e = blockIdx.x * 256 + threadIdx.x;
    if (e < N_EDGES) atomicAdd(&degc[dst[e]], 1);
}

__global__ void compute_dinv(const int* __restrict__ degc, float* __restrict__ dinv) {
    int i = blockIdx.x * 256 + threadIdx.x;
    if (i < N_NODES) dinv[i] = rsqrtf(1.0f + (float)degc[i]);
}

// 3-phase exclusive scan of degc -> rowp  (chunk = 256)
__global__ void scan_partial(const int* __restrict__ cnt, int* __restrict__ partial) {
    __shared__ int s[256];
    int t = threadIdx.x;
    int i = blockIdx.x * 256 + t;
    int v = (i < N_NODES) ? cnt[i] : 0;
    s[t] = v; __syncthreads();
    for (int off = 128; off > 0; off >>= 1) {
        if (t < off) s[t] += s[t + off];
        __syncthreads();
    }
    if (t == 0) partial[blockIdx.x] = s[0];
}

__global__ void scan_offsets(int* __restrict__ partial, int nb, int* __restrict__ rowp) {
    __shared__ int s[512];
    int t = threadIdx.x;                  // 512 threads
    int orig = (t < nb) ? partial[t] : 0;
    s[t] = orig; __syncthreads();
    for (int off = 1; off < 512; off <<= 1) {
        int u = (t >= off) ? s[t - off] : 0;
        __syncthreads();
        s[t] += u;
        __syncthreads();
    }
    if (t < nb) partial[t] = s[t] - orig; // exclusive chunk offsets
    if (t == 0) rowp[N_NODES] = N_EDGES;
}

__global__ void scan_final(const int* __restrict__ cnt, const int* __restrict__ partial,
                           int* __restrict__ rowp) {
    __shared__ int s[256];
    int t = threadIdx.x;
    int i = blockIdx.x * 256 + t;
    int v = (i < N_NODES) ? cnt[i] : 0;
    s[t] = v; __syncthreads();
    for (int off = 1; off < 256; off <<= 1) {
        int u = (t >= off) ? s[t - off] : 0;
        __syncthreads();
        s[t] += u;
        __syncthreads();
    }
    if (i < N_NODES) rowp[i] = partial[blockIdx.x] + s[t] - v;
}

__global__ void init_cursor(const int* __restrict__ rowp, int* __restrict__ cur) {
    int i = blockIdx.x * 256 + threadIdx.x;
    if (i < N_NODES) cur[i] = rowp[i];
}

__global__ void scatter_edges(const int* __restrict__ src, const int* __restrict__ dst,
                              int* __restrict__ cur, int* __restrict__ esrc) {
    int e = blockIdx.x * 256 + threadIdx.x;
    if (e < N_EDGES) {
        int d = dst[e];
        int pos = atomicAdd(&cur[d], 1);
        esrc[pos] = src[e];
    }
}

// lower_bound per graph id (batch is sorted)
__global__ void graph_offsets(const int* __restrict__ batch, int* __restrict__ goff) {
    int g = blockIdx.x * 256 + threadIdx.x;
    if (g > G_GR) return;
    int lo = 0, hi = N_NODES;
    while (lo < hi) {
        int mid = (lo + hi) >> 1;
        if (batch[mid] < g) lo = mid + 1; else hi = mid;
    }
    goff[g] = lo;
}

// ---------------- GEMM: C[M x 256] = A[M x K] @ W[K x 256], C stored bf16 ----------------
// 64x64 tile, 256 threads, 4x4 per thread, BK=16.
template <bool BF16A>
__global__ void gemm_to_bf16(const void* __restrict__ Av, const float* __restrict__ W,
                             u16* __restrict__ C, int M, int K) {
    __shared__ float As[16][68];
    __shared__ float Ws[16][68];
    const int bm = blockIdx.x * 64;
    const int bn = blockIdx.y * 64;
    const int tid = threadIdx.x;
    const int tx = tid & 15;        // col group
    const int ty = tid >> 4;        // row group
    const int lr = tid >> 2;        // 0..63 : A-tile row
    const int lk = (tid & 3) * 4;   // A-tile k offset
    const int wk = tid >> 4;        // 0..15 : W-tile row
    const int wn = (tid & 15) * 4;  // W-tile col offset

    float acc[4][4] = {};

    for (int k0 = 0; k0 < K; k0 += 16) {
        float a0, a1, a2, a3;
        int r = bm + lr;
        if (r < M) {
            if (BF16A) {
                const u16* A = (const u16*)Av;
                ushort4 u = *(const ushort4*)&A[(size_t)r * K + k0 + lk];
                a0 = bf2f(u.x); a1 = bf2f(u.y); a2 = bf2f(u.z); a3 = bf2f(u.w);
            } else {
                const float* A = (const float*)Av;
                float4 f = *(const float4*)&A[(size_t)r * K + k0 + lk];
                a0 = f.x; a1 = f.y; a2 = f.z; a3 = f.w;
            }
        } else { a0 = a1 = a2 = a3 = 0.f; }
        As[lk + 0][lr] = a0; As[lk + 1][lr] = a1;
        As[lk + 2][lr] = a2; As[lk + 3][lr] = a3;

        float4 wf = *(const float4*)&W[(size_t)(k0 + wk) * H + bn + wn];
        Ws[wk][wn + 0] = wf.x; Ws[wk][wn + 1] = wf.y;
        Ws[wk][wn + 2] = wf.z; Ws[wk][wn + 3] = wf.w;
        __syncthreads();

#pragma unroll
        for (int kk = 0; kk < 16; kk++) {
            float4 av = *(const float4*)&As[kk][ty * 4];
            float4 bv = *(const float4*)&Ws[kk][tx * 4];
            float a[4] = { av.x, av.y, av.z, av.w };
            float b[4] = { bv.x, bv.y, bv.z, bv.w };
#pragma unroll
            for (int i = 0; i < 4; i++)
#pragma unroll
                for (int j = 0; j < 4; j++)
                    acc[i][j] += a[i] * b[j];
        }
        __syncthreads();
    }

#pragma unroll
    for (int i = 0; i < 4; i++) {
        int r = bm + ty * 4 + i;
        if (r < M) {
            ushort4 u;
            u.x = f2bf(acc[i][0]); u.y = f2bf(acc[i][1]);
            u.z = f2bf(acc[i][2]); u.w = f2bf(acc[i][3]);
            *(ushort4*)&C[(size_t)r * H + bn + tx * 4] = u;
        }
    }
}

// ---------------- GCN aggregation: one block per node, thread j = feature j ----------------
__global__ void gcn_aggregate(const u16* __restrict__ hw, const int* __restrict__ rowp,
                              const int* __restrict__ esrc, const float* __restrict__ dinv,
                              const float* __restrict__ bias, u16* __restrict__ hout,
                              int do_relu) {
    int node = blockIdx.x;
    int j = threadIdx.x;
    float di = dinv[node];
    float acc = bf2f(hw[(size_t)node * H + j]) * (di * di);  // self-loop term
    int beg = rowp[node], end = rowp[node + 1];
    for (int e = beg; e < end; e++) {
        int s = esrc[e];
        float w = dinv[s] * di;
        acc += bf2f(hw[(size_t)s * H + j]) * w;
    }
    acc += bias[j];
    if (do_relu) acc = fmaxf(acc, 0.f);
    hout[(size_t)node * H + j] = f2bf(acc);
}

// ---------------- mean pool over contiguous node ranges ----------------
__global__ void pool_mean(const u16* __restrict__ h, const int* __restrict__ goff,
                          float* __restrict__ pooled) {
    int g = blockIdx.x;
    int j = threadIdx.x;
    int beg = goff[g], end = goff[g + 1];
    float acc = 0.f;
    for (int i = beg; i < end; i++) acc += bf2f(h[(size_t)i * H + j]);
    float c = (float)(end - beg);
    pooled[g * H + j] = acc / fmaxf(c, 1.f);
}

// ---------------- MLP ----------------
__global__ void mlp1(const float* __restrict__ pooled, const float* __restrict__ Wm1,
                     const float* __restrict__ bm1, float* __restrict__ hidden) {
    __shared__ float p[H];
    int g = blockIdx.x, t = threadIdx.x;
    p[t] = pooled[g * H + t];
    __syncthreads();
#pragma unroll
    for (int rep = 0; rep < 2; rep++) {
        int o = rep * 256 + t;
        float acc = bm1[o];
        for (int k = 0; k < H; k++) acc += p[k] * Wm1[(size_t)k * NHID + o];
        hidden[g * NHID + o] = fmaxf(acc, 0.f);
    }
}

__global__ void mlp2(const float* __restrict__ hidden, const float* __restrict__ Wm2,
                     const float* __restrict__ bm2, float* __restrict__ out) {
    __shared__ float p[NHID];
    int g = blockIdx.x, t = threadIdx.x;
    p[t] = hidden[g * NHID + t];
    p[t + 256] = hidden[g * NHID + t + 256];
    __syncthreads();
    float acc = bm2[t];
    for (int k = 0; k < NHID; k++) acc += p[k] * Wm2[(size_t)k * NOUT + t];
    out[g * NOUT + t] = acc;
}

// ---------------- launch ----------------
extern "C" void kernel_launch(void* const* d_in, const int* in_sizes, int n_in,
                              void* d_out, int out_size, void* d_ws, size_t ws_size,
                              hipStream_t stream) {
    const float* x   = (const float*)d_in[0];
    const int*   src = (const int*)d_in[1];
    const int*   dst = (const int*)d_in[2];
    const int*   bat = (const int*)d_in[3];
    const float* W1  = (const float*)d_in[4];  const float* b1  = (const float*)d_in[5];
    const float* W2  = (const float*)d_in[6];  const float* b2  = (const float*)d_in[7];
    const float* W3  = (const float*)d_in[8];  const float* b3  = (const float*)d_in[9];
    const float* Wm1 = (const float*)d_in[10]; const float* bm1 = (const float*)d_in[11];
    const float* Wm2 = (const float*)d_in[12]; const float* bm2 = (const float*)d_in[13];
    float* out = (float*)d_out;

    char* p = (char*)d_ws;
    auto carve = [&](size_t bytes) -> void* {
        void* r = (void*)p;
        p += (bytes + 511) & ~(size_t)511;
        return r;
    };
    u16*   hw      = (u16*)  carve((size_t)N_NODES * H * 2);
    u16*   h       = (u16*)  carve((size_t)N_NODES * H * 2);
    float* dinv    = (float*)carve((size_t)N_NODES * 4);
    int*   degc    = (int*)  carve((size_t)N_NODES * 4);
    int*   rowp    = (int*)  carve((size_t)(N_NODES + 1) * 4);
    int*   cur     = (int*)  carve((size_t)N_NODES * 4);
    int*   esrc    = (int*)  carve((size_t)N_EDGES * 4);
    int*   partial = (int*)  carve(4096);
    int*   goff    = (int*)  carve((size_t)(G_GR + 1) * 4);
    float* pooled  = (float*)carve((size_t)G_GR * H * 4);
    float* hidden  = (float*)carve((size_t)G_GR * NHID * 4);

    const int NB = (N_NODES + 255) / 256;   // 391 scan chunks
    const int EB = (N_EDGES + 255) / 256;

    hipMemsetAsync(degc, 0, (size_t)N_NODES * 4, stream);
    count_deg<<<EB, 256, 0, stream>>>(dst, degc);
    compute_dinv<<<NB, 256, 0, stream>>>(degc, dinv);
    scan_partial<<<NB, 256, 0, stream>>>(degc, partial);
    scan_offsets<<<1, 512, 0, stream>>>(partial, NB, rowp);
    scan_final<<<NB, 256, 0, stream>>>(degc, partial, rowp);
    init_cursor<<<NB, 256, 0, stream>>>(rowp, cur);
    scatter_edges<<<EB, 256, 0, stream>>>(src, dst, cur, esrc);
    graph_offsets<<<2, 256, 0, stream>>>(bat, goff);

    dim3 ggrid((N_NODES + 63) / 64, H / 64);

    // layer 1
    gemm_to_bf16<false><<<ggrid, 256, 0, stream>>>((const void*)x, W1, hw, N_NODES, F_IN);
    gcn_aggregate<<<N_NODES, 256, 0, stream>>>(hw, rowp, esrc, dinv, b1, h, 1);
    // layer 2
    gemm_to_bf16<true><<<ggrid, 256, 0, stream>>>((const void*)h, W2, hw, N_NODES, H);
    gcn_aggregate<<<N_NODES, 256, 0, stream>>>(hw, rowp, esrc, dinv, b2, h, 1);
    // layer 3
    gemm_to_bf16<true><<<ggrid, 256, 0, stream>>>((const void*)h, W3, hw, N_NODES, H);
    gcn_aggregate<<<N_NODES, 256, 0, stream>>>(hw, rowp, esrc, dinv, b3, h, 0);

    pool_mean<<<G_GR, 256, 0, stream>>>(h, goff, pooled);
    mlp1<<<G_GR, 256, 0, stream>>>(pooled, Wm1, bm1, hidden);
    mlp2<<<G_GR, 256, 0, stream>>>(hidden, Wm2, bm2, out);
}

// Round 3
// 1189.092 us; speedup vs baseline: 1.5443x; 1.5443x over previous
//
#include <hip/hip_runtime.h>
#include <hip/hip_bf16.h>

#define N_NODES 100000
#define N_EDGES 1600000
#define F_IN    128
#define H       256
#define NHID    512
#define NOUT    256
#define G_GR    256

typedef unsigned short u16;
typedef __attribute__((ext_vector_type(8))) short s16x8;          // 8 bf16 (MFMA operand)
typedef __attribute__((ext_vector_type(8))) unsigned short u16x8; // 16B load/store
typedef __attribute__((ext_vector_type(4))) float f32x4;          // MFMA acc

__device__ __forceinline__ float bf2f(u16 u) {
    union { unsigned int i; float f; } v; v.i = ((unsigned int)u) << 16; return v.f;
}
__device__ __forceinline__ u16 f2bf(float f) {
    union { float f; unsigned int i; } v; v.f = f;
    unsigned int x = v.i;
    x += 0x7fffu + ((x >> 16) & 1u);   // round-to-nearest-even
    return (u16)(x >> 16);
}

// ---------------- graph prep ----------------

__global__ void count_deg(const int* __restrict__ dst, int* __restrict__ degc) {
    int e = blockIdx.x * 256 + threadIdx.x;
    if (e < N_EDGES) atomicAdd(&degc[dst[e]], 1);
}

__global__ void compute_dinv(const int* __restrict__ degc, float* __restrict__ dinv) {
    int i = blockIdx.x * 256 + threadIdx.x;
    if (i < N_NODES) dinv[i] = rsqrtf(1.0f + (float)degc[i]);
}

__global__ void scan_partial(const int* __restrict__ cnt, int* __restrict__ partial) {
    __shared__ int s[256];
    int t = threadIdx.x;
    int i = blockIdx.x * 256 + t;
    int v = (i < N_NODES) ? cnt[i] : 0;
    s[t] = v; __syncthreads();
    for (int off = 128; off > 0; off >>= 1) {
        if (t < off) s[t] += s[t + off];
        __syncthreads();
    }
    if (t == 0) partial[blockIdx.x] = s[0];
}

__global__ void scan_offsets(int* __restrict__ partial, int nb, int* __restrict__ rowp) {
    __shared__ int s[512];
    int t = threadIdx.x;
    int orig = (t < nb) ? partial[t] : 0;
    s[t] = orig; __syncthreads();
    for (int off = 1; off < 512; off <<= 1) {
        int u = (t >= off) ? s[t - off] : 0;
        __syncthreads();
        s[t] += u;
        __syncthreads();
    }
    if (t < nb) partial[t] = s[t] - orig;
    if (t == 0) rowp[N_NODES] = N_EDGES;
}

__global__ void scan_final(const int* __restrict__ cnt, const int* __restrict__ partial,
                           int* __restrict__ rowp) {
    __shared__ int s[256];
    int t = threadIdx.x;
    int i = blockIdx.x * 256 + t;
    int v = (i < N_NODES) ? cnt[i] : 0;
    s[t] = v; __syncthreads();
    for (int off = 1; off < 256; off <<= 1) {
        int u = (t >= off) ? s[t - off] : 0;
        __syncthreads();
        s[t] += u;
        __syncthreads();
    }
    if (i < N_NODES) rowp[i] = partial[blockIdx.x] + s[t] - v;
}

__global__ void init_cursor(const int* __restrict__ rowp, int* __restrict__ cur) {
    int i = blockIdx.x * 256 + threadIdx.x;
    if (i < N_NODES) cur[i] = rowp[i];
}

__global__ void scatter_edges(const int* __restrict__ src, const int* __restrict__ dst,
                              int* __restrict__ cur, int* __restrict__ esrc) {
    int e = blockIdx.x * 256 + threadIdx.x;
    if (e < N_EDGES) {
        int d = dst[e];
        int pos = atomicAdd(&cur[d], 1);
        esrc[pos] = src[e];
    }
}

__global__ void graph_offsets(const int* __restrict__ batch, int* __restrict__ goff) {
    int g = blockIdx.x * 256 + threadIdx.x;
    if (g > G_GR) return;
    int lo = 0, hi = N_NODES;
    while (lo < hi) {
        int mid = (lo + hi) >> 1;
        if (batch[mid] < g) lo = mid + 1; else hi = mid;
    }
    goff[g] = lo;
}

// ---------------- precision-split conversion ----------------

__global__ void split_f32(const float* __restrict__ in, u16* __restrict__ hi,
                          u16* __restrict__ lo, int n) {
    int i = blockIdx.x * 256 + threadIdx.x;
    if (i < n) {
        float f = in[i];
        u16 h = f2bf(f);
        hi[i] = h;
        lo[i] = f2bf(f - bf2f(h));
    }
}

// W[K][N] fp32 -> Wt_hi[N][K], Wt_lo[N][K] bf16 (transposed for B-fragment layout)
__global__ void transpose_split(const float* __restrict__ W, u16* __restrict__ thi,
                                u16* __restrict__ tlo, int K, int N) {
    int id = blockIdx.x * 256 + threadIdx.x;
    if (id >= K * N) return;
    int n = id / K, k = id - n * K;
    float f = W[(size_t)k * N + n];
    u16 h = f2bf(f);
    thi[id] = h;
    tlo[id] = f2bf(f - bf2f(h));
}

// ---------------- MFMA GEMM: C[M x 256] = (Ahi+Alo)[M x K] @ (Whi+Wlo)[K x 256] ----------------
// 128x128 tile, 256 threads (4 waves, each 64x64 = 4x4 frags of 16x16x32 bf16).
// B passed pre-transposed as Wt[N][K] so A and B fragments share the LDS pattern.
template<int K, bool SPLIT_A>
__global__ __launch_bounds__(256) void gemm_mfma(
        const u16* __restrict__ Ahi, const u16* __restrict__ Alo,
        const u16* __restrict__ Bhi, const u16* __restrict__ Blo,
        u16* __restrict__ C, int M) {
    __shared__ __align__(16) u16 sA[(SPLIT_A ? 2 : 1) * 128 * 40];
    __shared__ __align__(16) u16 sB[2 * 128 * 40];
    const int tid = threadIdx.x;
    const int w = tid >> 6, l = tid & 63;
    const int wm = (w & 1) * 64, wn = (w >> 1) * 64;
    const int bm = blockIdx.x * 128, bn = blockIdx.y * 128;
    const int srow = tid >> 2;         // 0..63
    const int schunk = (tid & 3) * 8;  // 0,8,16,24  (covers all 32 k-elems)
    const int lr = l & 15, lg = (l >> 4) * 8;

    f32x4 acc[4][4] = {};

    for (int k0 = 0; k0 < K; k0 += 32) {
        // stage A tile rows [bm, bm+128), k [k0, k0+32). Two row-halves per thread.
        {
            int r0 = bm + srow, r1 = bm + srow + 64;
            u16x8 v0 = {}, v1 = {};
            if (r0 < M) v0 = *(const u16x8*)&Ahi[(size_t)r0 * K + k0 + schunk];
            if (r1 < M) v1 = *(const u16x8*)&Ahi[(size_t)r1 * K + k0 + schunk];
            *(u16x8*)&sA[srow * 40 + schunk] = v0;
            *(u16x8*)&sA[(srow + 64) * 40 + schunk] = v1;
            if (SPLIT_A) {
                u16x8 w0 = {}, w1 = {};
                if (r0 < M) w0 = *(const u16x8*)&Alo[(size_t)r0 * K + k0 + schunk];
                if (r1 < M) w1 = *(const u16x8*)&Alo[(size_t)r1 * K + k0 + schunk];
                *(u16x8*)&sA[128 * 40 + srow * 40 + schunk] = w0;
                *(u16x8*)&sA[128 * 40 + (srow + 64) * 40 + schunk] = w1;
            }
        }
        // stage B tiles (Wt rows [bn, bn+128), k [k0, k0+32)), hi + lo
        {
            int n0 = bn + srow, n1 = bn + srow + 64;
            *(u16x8*)&sB[srow * 40 + schunk] =
                *(const u16x8*)&Bhi[(size_t)n0 * K + k0 + schunk];
            *(u16x8*)&sB[(srow + 64) * 40 + schunk] =
                *(const u16x8*)&Bhi[(size_t)n1 * K + k0 + schunk];
            *(u16x8*)&sB[128 * 40 + srow * 40 + schunk] =
                *(const u16x8*)&Blo[(size_t)n0 * K + k0 + schunk];
            *(u16x8*)&sB[128 * 40 + (srow + 64) * 40 + schunk] =
                *(const u16x8*)&Blo[(size_t)n1 * K + k0 + schunk];
        }
        __syncthreads();

        s16x8 af[4], bh[4], bl[4], al[4];
#pragma unroll
        for (int i = 0; i < 4; i++)
            af[i] = __builtin_bit_cast(s16x8, *(const u16x8*)&sA[(wm + i * 16 + lr) * 40 + lg]);
        if (SPLIT_A) {
#pragma unroll
            for (int i = 0; i < 4; i++)
                al[i] = __builtin_bit_cast(s16x8,
                        *(const u16x8*)&sA[128 * 40 + (wm + i * 16 + lr) * 40 + lg]);
        }
#pragma unroll
        for (int j = 0; j < 4; j++) {
            bh[j] = __builtin_bit_cast(s16x8, *(const u16x8*)&sB[(wn + j * 16 + lr) * 40 + lg]);
            bl[j] = __builtin_bit_cast(s16x8,
                    *(const u16x8*)&sB[128 * 40 + (wn + j * 16 + lr) * 40 + lg]);
        }
#pragma unroll
        for (int i = 0; i < 4; i++) {
#pragma unroll
            for (int j = 0; j < 4; j++) {
                acc[i][j] = __builtin_amdgcn_mfma_f32_16x16x32_bf16(af[i], bh[j], acc[i][j], 0, 0, 0);
                acc[i][j] = __builtin_amdgcn_mfma_f32_16x16x32_bf16(af[i], bl[j], acc[i][j], 0, 0, 0);
                if (SPLIT_A)
                    acc[i][j] = __builtin_amdgcn_mfma_f32_16x16x32_bf16(al[i], bh[j], acc[i][j], 0, 0, 0);
            }
        }
        __syncthreads();
    }

    // C/D layout: col = lane&15, row = (lane>>4)*4 + reg
    const int lq = (l >> 4) * 4;
#pragma unroll
    for (int i = 0; i < 4; i++) {
#pragma unroll
        for (int r0 = 0; r0 < 4; r0++) {
            int row = bm + wm + i * 16 + lq + r0;
            if (row < M) {
#pragma unroll
                for (int j = 0; j < 4; j++)
                    C[(size_t)row * H + bn + wn + j * 16 + lr] = f2bf(acc[i][j][r0]);
            }
        }
    }
}

// ---------------- GCN aggregation: block per node, wave per edge-row ----------------
__global__ __launch_bounds__(256) void gcn_aggregate(
        const u16* __restrict__ hw, const int* __restrict__ rowp,
        const int* __restrict__ esrc, const float* __restrict__ dinv,
        const float* __restrict__ bias, u16* __restrict__ hout, int do_relu) {
    __shared__ float sm[4][256];
    int node = blockIdx.x;
    int w = threadIdx.x >> 6;
    int l = threadIdx.x & 63;
    float di = dinv[node];
    int beg = rowp[node], end = rowp[node + 1];

    float4 acc = { 0.f, 0.f, 0.f, 0.f };
    int e = beg + w;
    int s_next = (e < end) ? esrc[e] : 0;
    while (e < end) {
        int s = s_next;
        int e2 = e + 4;
        s_next = (e2 < end) ? esrc[e2] : 0;
        float wt = dinv[s] * di;
        ushort4 u = *(const ushort4*)&hw[(size_t)s * H + l * 4];
        acc.x += bf2f(u.x) * wt;
        acc.y += bf2f(u.y) * wt;
        acc.z += bf2f(u.z) * wt;
        acc.w += bf2f(u.w) * wt;
        e = e2;
    }
    sm[w][l * 4 + 0] = acc.x;
    sm[w][l * 4 + 1] = acc.y;
    sm[w][l * 4 + 2] = acc.z;
    sm[w][l * 4 + 3] = acc.w;
    __syncthreads();

    int t = threadIdx.x;
    float v = sm[0][t] + sm[1][t] + sm[2][t] + sm[3][t];
    v += bf2f(hw[(size_t)node * H + t]) * (di * di) + bias[t];
    if (do_relu) v = fmaxf(v, 0.f);
    hout[(size_t)node * H + t] = f2bf(v);
}

// ---------------- mean pool ----------------
__global__ void pool_mean(const u16* __restrict__ h, const int* __restrict__ goff,
                          float* __restrict__ pooled) {
    int g = blockIdx.x;
    int j = threadIdx.x;
    int beg = goff[g], end = goff[g + 1];
    float acc = 0.f;
    for (int i = beg; i < end; i++) acc += bf2f(h[(size_t)i * H + j]);
    float c = (float)(end - beg);
    pooled[g * H + j] = acc / fmaxf(c, 1.f);
}

// ---------------- MLP ----------------
__global__ void mlp1(const float* __restrict__ pooled, const float* __restrict__ Wm1,
                     const float* __restrict__ bm1, float* __restrict__ hidden) {
    __shared__ float p[H];
    int g = blockIdx.x, t = threadIdx.x;
    p[t] = pooled[g * H + t];
    __syncthreads();
#pragma unroll
    for (int rep = 0; rep < 2; rep++) {
        int o = rep * 256 + t;
        float acc = bm1[o];
        for (int k = 0; k < H; k++) acc += p[k] * Wm1[(size_t)k * NHID + o];
        hidden[g * NHID + o] = fmaxf(acc, 0.f);
    }
}

__global__ void mlp2(const float* __restrict__ hidden, const float* __restrict__ Wm2,
                     const float* __restrict__ bm2, float* __restrict__ out) {
    __shared__ float p[NHID];
    int g = blockIdx.x, t = threadIdx.x;
    p[t] = hidden[g * NHID + t];
    p[t + 256] = hidden[g * NHID + t + 256];
    __syncthreads();
    float acc = bm2[t];
    for (int k = 0; k < NHID; k++) acc += p[k] * Wm2[(size_t)k * NOUT + t];
    out[g * NOUT + t] = acc;
}

// ---------------- launch ----------------
extern "C" void kernel_launch(void* const* d_in, const int* in_sizes, int n_in,
                              void* d_out, int out_size, void* d_ws, size_t ws_size,
                              hipStream_t stream) {
    const float* x   = (const float*)d_in[0];
    const int*   src = (const int*)d_in[1];
    const int*   dst = (const int*)d_in[2];
    const int*   bat = (const int*)d_in[3];
    const float* W1  = (const float*)d_in[4];  const float* b1  = (const float*)d_in[5];
    const float* W2  = (const float*)d_in[6];  const float* b2  = (const float*)d_in[7];
    const float* W3  = (const float*)d_in[8];  const float* b3  = (const float*)d_in[9];
    const float* Wm1 = (const float*)d_in[10]; const float* bm1 = (const float*)d_in[11];
    const float* Wm2 = (const float*)d_in[12]; const float* bm2 = (const float*)d_in[13];
    float* out = (float*)d_out;

    char* p = (char*)d_ws;
    auto carve = [&](size_t bytes) -> void* {
        void* r = (void*)p;
        p += (bytes + 511) & ~(size_t)511;
        return r;
    };
    u16*   hw      = (u16*)  carve((size_t)N_NODES * H * 2);
    u16*   h       = (u16*)  carve((size_t)N_NODES * H * 2);
    float* dinv    = (float*)carve((size_t)N_NODES * 4);
    int*   degc    = (int*)  carve((size_t)N_NODES * 4);
    int*   rowp    = (int*)  carve((size_t)(N_NODES + 1) * 4);
    int*   cur     = (int*)  carve((size_t)N_NODES * 4);
    int*   esrc    = (int*)  carve((size_t)N_EDGES * 4);
    int*   partial = (int*)  carve(4096);
    int*   goff    = (int*)  carve((size_t)(G_GR + 1) * 4);
    float* pooled  = (float*)carve((size_t)G_GR * H * 4);
    float* hidden  = (float*)carve((size_t)G_GR * NHID * 4);
    u16*   Wt1_hi  = (u16*)  carve((size_t)F_IN * H * 2);
    u16*   Wt1_lo  = (u16*)  carve((size_t)F_IN * H * 2);
    u16*   Wt2_hi  = (u16*)  carve((size_t)H * H * 2);
    u16*   Wt2_lo  = (u16*)  carve((size_t)H * H * 2);
    u16*   Wt3_hi  = (u16*)  carve((size_t)H * H * 2);
    u16*   Wt3_lo  = (u16*)  carve((size_t)H * H * 2);
    // x_hi/x_lo alias the h buffer (dead until aggregate L1 writes it, after L1 GEMM reads these)
    u16*   x_hi    = h;
    u16*   x_lo    = h + (size_t)N_NODES * F_IN;

    const int NB = (N_NODES + 255) / 256;
    const int EB = (N_EDGES + 255) / 256;

    hipMemsetAsync(degc, 0, (size_t)N_NODES * 4, stream);
    count_deg<<<EB, 256, 0, stream>>>(dst, degc);
    compute_dinv<<<NB, 256, 0, stream>>>(degc, dinv);
    scan_partial<<<NB, 256, 0, stream>>>(degc, partial);
    scan_offsets<<<1, 512, 0, stream>>>(partial, NB, rowp);
    scan_final<<<NB, 256, 0, stream>>>(degc, partial, rowp);
    init_cursor<<<NB, 256, 0, stream>>>(rowp, cur);
    scatter_edges<<<EB, 256, 0, stream>>>(src, dst, cur, esrc);
    graph_offsets<<<2, 256, 0, stream>>>(bat, goff);

    split_f32<<<(N_NODES * F_IN + 255) / 256, 256, 0, stream>>>(x, x_hi, x_lo, N_NODES * F_IN);
    transpose_split<<<(F_IN * H + 255) / 256, 256, 0, stream>>>(W1, Wt1_hi, Wt1_lo, F_IN, H);
    transpose_split<<<(H * H + 255) / 256, 256, 0, stream>>>(W2, Wt2_hi, Wt2_lo, H, H);
    transpose_split<<<(H * H + 255) / 256, 256, 0, stream>>>(W3, Wt3_hi, Wt3_lo, H, H);

    dim3 ggrid((N_NODES + 127) / 128, 2);

    // layer 1 (A split: x_hi + x_lo)
    gemm_mfma<F_IN, true><<<ggrid, 256, 0, stream>>>(x_hi, x_lo, Wt1_hi, Wt1_lo, hw, N_NODES);
    gcn_aggregate<<<N_NODES, 256, 0, stream>>>(hw, rowp, esrc, dinv, b1, h, 1);
    // layer 2
    gemm_mfma<H, false><<<ggrid, 256, 0, stream>>>(h, h, Wt2_hi, Wt2_lo, hw, N_NODES);
    gcn_aggregate<<<N_NODES, 256, 0, stream>>>(hw, rowp, esrc, dinv, b2, h, 1);
    // layer 3
    gemm_mfma<H, false><<<ggrid, 256, 0, stream>>>(h, h, Wt3_hi, Wt3_lo, hw, N_NODES);
    gcn_aggregate<<<N_NODES, 256, 0, stream>>>(hw, rowp, esrc, dinv, b3, h, 0);

    pool_mean<<<G_GR, 256, 0, stream>>>(h, goff, pooled);
    mlp1<<<G_GR, 256, 0, stream>>>(pooled, Wm1, bm1, hidden);
    mlp2<<<G_GR, 256, 0, stream>>>(hidden, Wm2, bm2, out);
}

// Round 4
// 970.215 us; speedup vs baseline: 1.8927x; 1.2256x over previous
//
#include <hip/hip_runtime.h>
#include <hip/hip_bf16.h>

#define N_NODES 100000
#define N_EDGES 1600000
#define F_IN    128
#define H       256
#define NHID    512
#define NOUT    256
#define G_GR    256

typedef unsigned short u16;
typedef __attribute__((ext_vector_type(8))) short s16x8;          // 8 bf16 (MFMA operand)
typedef __attribute__((ext_vector_type(8))) unsigned short u16x8; // 16B load/store
typedef __attribute__((ext_vector_type(4))) float f32x4;          // MFMA acc

__device__ __forceinline__ float bf2f(u16 u) {
    union { unsigned int i; float f; } v; v.i = ((unsigned int)u) << 16; return v.f;
}
__device__ __forceinline__ u16 f2bf(float f) {
    union { float f; unsigned int i; } v; v.f = f;
    unsigned int x = v.i;
    x += 0x7fffu + ((x >> 16) & 1u);   // round-to-nearest-even
    return (u16)(x >> 16);
}

// ---------------- graph prep ----------------

__global__ void count_deg(const int* __restrict__ dst, int* __restrict__ degc) {
    int e = blockIdx.x * 256 + threadIdx.x;
    if (e < N_EDGES) atomicAdd(&degc[dst[e]], 1);
}

__global__ void compute_dinv(const int* __restrict__ degc, float* __restrict__ dinv) {
    int i = blockIdx.x * 256 + threadIdx.x;
    if (i < N_NODES) dinv[i] = rsqrtf(1.0f + (float)degc[i]);
}

__global__ void scan_partial(const int* __restrict__ cnt, int* __restrict__ partial) {
    __shared__ int s[256];
    int t = threadIdx.x;
    int i = blockIdx.x * 256 + t;
    int v = (i < N_NODES) ? cnt[i] : 0;
    s[t] = v; __syncthreads();
    for (int off = 128; off > 0; off >>= 1) {
        if (t < off) s[t] += s[t + off];
        __syncthreads();
    }
    if (t == 0) partial[blockIdx.x] = s[0];
}

__global__ void scan_offsets(int* __restrict__ partial, int nb, int* __restrict__ rowp) {
    __shared__ int s[512];
    int t = threadIdx.x;
    int orig = (t < nb) ? partial[t] : 0;
    s[t] = orig; __syncthreads();
    for (int off = 1; off < 512; off <<= 1) {
        int u = (t >= off) ? s[t - off] : 0;
        __syncthreads();
        s[t] += u;
        __syncthreads();
    }
    if (t < nb) partial[t] = s[t] - orig;
    if (t == 0) rowp[N_NODES] = N_EDGES;
}

__global__ void scan_final(const int* __restrict__ cnt, const int* __restrict__ partial,
                           int* __restrict__ rowp) {
    __shared__ int s[256];
    int t = threadIdx.x;
    int i = blockIdx.x * 256 + t;
    int v = (i < N_NODES) ? cnt[i] : 0;
    s[t] = v; __syncthreads();
    for (int off = 1; off < 256; off <<= 1) {
        int u = (t >= off) ? s[t - off] : 0;
        __syncthreads();
        s[t] += u;
        __syncthreads();
    }
    if (i < N_NODES) rowp[i] = partial[blockIdx.x] + s[t] - v;
}

__global__ void init_cursor(const int* __restrict__ rowp, int* __restrict__ cur) {
    int i = blockIdx.x * 256 + threadIdx.x;
    if (i < N_NODES) cur[i] = rowp[i];
}

__global__ void scatter_edges(const int* __restrict__ src, const int* __restrict__ dst,
                              int* __restrict__ cur, int* __restrict__ esrc) {
    int e = blockIdx.x * 256 + threadIdx.x;
    if (e < N_EDGES) {
        int d = dst[e];
        int pos = atomicAdd(&cur[d], 1);
        esrc[pos] = src[e];
    }
}

__global__ void graph_offsets(const int* __restrict__ batch, int* __restrict__ goff) {
    int g = blockIdx.x * 256 + threadIdx.x;
    if (g > G_GR) return;
    int lo = 0, hi = N_NODES;
    while (lo < hi) {
        int mid = (lo + hi) >> 1;
        if (batch[mid] < g) lo = mid + 1; else hi = mid;
    }
    goff[g] = lo;
}

// ---------------- precision-split conversion ----------------

__global__ void split_f32(const float* __restrict__ in, u16* __restrict__ hi,
                          u16* __restrict__ lo, int n) {
    int i = blockIdx.x * 256 + threadIdx.x;
    if (i < n) {
        float f = in[i];
        u16 h = f2bf(f);
        hi[i] = h;
        lo[i] = f2bf(f - bf2f(h));
    }
}

// W[K][N] fp32 -> Wt_hi[N][K], Wt_lo[N][K] bf16 (transposed for B-fragment layout)
__global__ void transpose_split(const float* __restrict__ W, u16* __restrict__ thi,
                                u16* __restrict__ tlo, int K, int N) {
    int id = blockIdx.x * 256 + threadIdx.x;
    if (id >= K * N) return;
    int n = id / K, k = id - n * K;
    float f = W[(size_t)k * N + n];
    u16 h = f2bf(f);
    thi[id] = h;
    tlo[id] = f2bf(f - bf2f(h));
}

// ---------------- MFMA GEMM: C[M x 256] = (Ahi+Alo)[M x K] @ (Whi+Wlo)[K x 256] ----------------
// 128x128 tile, 256 threads (4 waves, each 64x64 = 4x4 frags of 16x16x32 bf16).
// B passed pre-transposed as Wt[N][K] so A and B fragments share the LDS pattern.
template<int K, bool SPLIT_A>
__global__ __launch_bounds__(256) void gemm_mfma(
        const u16* __restrict__ Ahi, const u16* __restrict__ Alo,
        const u16* __restrict__ Bhi, const u16* __restrict__ Blo,
        u16* __restrict__ C, int M) {
    __shared__ __align__(16) u16 sA[(SPLIT_A ? 2 : 1) * 128 * 40];
    __shared__ __align__(16) u16 sB[2 * 128 * 40];
    const int tid = threadIdx.x;
    const int w = tid >> 6, l = tid & 63;
    const int wm = (w & 1) * 64, wn = (w >> 1) * 64;
    const int bm = blockIdx.x * 128, bn = blockIdx.y * 128;
    const int srow = tid >> 2;         // 0..63
    const int schunk = (tid & 3) * 8;  // 0,8,16,24  (covers all 32 k-elems)
    const int lr = l & 15, lg = (l >> 4) * 8;

    f32x4 acc[4][4] = {};

    for (int k0 = 0; k0 < K; k0 += 32) {
        // stage A tile rows [bm, bm+128), k [k0, k0+32). Two row-halves per thread.
        {
            int r0 = bm + srow, r1 = bm + srow + 64;
            u16x8 v0 = {}, v1 = {};
            if (r0 < M) v0 = *(const u16x8*)&Ahi[(size_t)r0 * K + k0 + schunk];
            if (r1 < M) v1 = *(const u16x8*)&Ahi[(size_t)r1 * K + k0 + schunk];
            *(u16x8*)&sA[srow * 40 + schunk] = v0;
            *(u16x8*)&sA[(srow + 64) * 40 + schunk] = v1;
            if (SPLIT_A) {
                u16x8 w0 = {}, w1 = {};
                if (r0 < M) w0 = *(const u16x8*)&Alo[(size_t)r0 * K + k0 + schunk];
                if (r1 < M) w1 = *(const u16x8*)&Alo[(size_t)r1 * K + k0 + schunk];
                *(u16x8*)&sA[128 * 40 + srow * 40 + schunk] = w0;
                *(u16x8*)&sA[128 * 40 + (srow + 64) * 40 + schunk] = w1;
            }
        }
        // stage B tiles (Wt rows [bn, bn+128), k [k0, k0+32)), hi + lo
        {
            int n0 = bn + srow, n1 = bn + srow + 64;
            *(u16x8*)&sB[srow * 40 + schunk] =
                *(const u16x8*)&Bhi[(size_t)n0 * K + k0 + schunk];
            *(u16x8*)&sB[(srow + 64) * 40 + schunk] =
                *(const u16x8*)&Bhi[(size_t)n1 * K + k0 + schunk];
            *(u16x8*)&sB[128 * 40 + srow * 40 + schunk] =
                *(const u16x8*)&Blo[(size_t)n0 * K + k0 + schunk];
            *(u16x8*)&sB[128 * 40 + (srow + 64) * 40 + schunk] =
                *(const u16x8*)&Blo[(size_t)n1 * K + k0 + schunk];
        }
        __syncthreads();

        s16x8 af[4], bh[4], bl[4], al[4];
#pragma unroll
        for (int i = 0; i < 4; i++)
            af[i] = __builtin_bit_cast(s16x8, *(const u16x8*)&sA[(wm + i * 16 + lr) * 40 + lg]);
        if (SPLIT_A) {
#pragma unroll
            for (int i = 0; i < 4; i++)
                al[i] = __builtin_bit_cast(s16x8,
                        *(const u16x8*)&sA[128 * 40 + (wm + i * 16 + lr) * 40 + lg]);
        }
#pragma unroll
        for (int j = 0; j < 4; j++) {
            bh[j] = __builtin_bit_cast(s16x8, *(const u16x8*)&sB[(wn + j * 16 + lr) * 40 + lg]);
            bl[j] = __builtin_bit_cast(s16x8,
                    *(const u16x8*)&sB[128 * 40 + (wn + j * 16 + lr) * 40 + lg]);
        }
#pragma unroll
        for (int i = 0; i < 4; i++) {
#pragma unroll
            for (int j = 0; j < 4; j++) {
                acc[i][j] = __builtin_amdgcn_mfma_f32_16x16x32_bf16(af[i], bh[j], acc[i][j], 0, 0, 0);
                acc[i][j] = __builtin_amdgcn_mfma_f32_16x16x32_bf16(af[i], bl[j], acc[i][j], 0, 0, 0);
                if (SPLIT_A)
                    acc[i][j] = __builtin_amdgcn_mfma_f32_16x16x32_bf16(al[i], bh[j], acc[i][j], 0, 0, 0);
            }
        }
        __syncthreads();
    }

    // C/D layout: col = lane&15, row = (lane>>4)*4 + reg
    const int lq = (l >> 4) * 4;
#pragma unroll
    for (int i = 0; i < 4; i++) {
#pragma unroll
        for (int r0 = 0; r0 < 4; r0++) {
            int row = bm + wm + i * 16 + lq + r0;
            if (row < M) {
#pragma unroll
                for (int j = 0; j < 4; j++)
                    C[(size_t)row * H + bn + wn + j * 16 + lr] = f2bf(acc[i][j][r0]);
            }
        }
    }
}

// ---------------- GCN aggregation: wave per node, 4-wide edge pipeline ----------------
// Lane l owns features [4l, 4l+4). No LDS, no __syncthreads.
__global__ __launch_bounds__(256) void gcn_aggregate(
        const u16* __restrict__ hw, const int* __restrict__ rowp,
        const int* __restrict__ esrc, const float* __restrict__ dinv,
        const float* __restrict__ bias, u16* __restrict__ hout, int do_relu) {
    int node = blockIdx.x * 4 + (threadIdx.x >> 6);
    int l = threadIdx.x & 63;
    float di = dinv[node];
    int beg = rowp[node], end = rowp[node + 1];

    float a0 = 0.f, a1 = 0.f, a2 = 0.f, a3 = 0.f;
    int e = beg;
    // 4-wide: 4 index loads + 4 dinv loads + 4 row loads (2 KB) in flight per wave
    for (; e + 4 <= end; e += 4) {
        int s0 = esrc[e], s1 = esrc[e + 1], s2 = esrc[e + 2], s3 = esrc[e + 3];
        float w0 = dinv[s0] * di, w1 = dinv[s1] * di;
        float w2 = dinv[s2] * di, w3 = dinv[s3] * di;
        ushort4 u0 = *(const ushort4*)&hw[(size_t)s0 * H + l * 4];
        ushort4 u1 = *(const ushort4*)&hw[(size_t)s1 * H + l * 4];
        ushort4 u2 = *(const ushort4*)&hw[(size_t)s2 * H + l * 4];
        ushort4 u3 = *(const ushort4*)&hw[(size_t)s3 * H + l * 4];
        a0 += bf2f(u0.x) * w0 + bf2f(u1.x) * w1 + bf2f(u2.x) * w2 + bf2f(u3.x) * w3;
        a1 += bf2f(u0.y) * w0 + bf2f(u1.y) * w1 + bf2f(u2.y) * w2 + bf2f(u3.y) * w3;
        a2 += bf2f(u0.z) * w0 + bf2f(u1.z) * w1 + bf2f(u2.z) * w2 + bf2f(u3.z) * w3;
        a3 += bf2f(u0.w) * w0 + bf2f(u1.w) * w1 + bf2f(u2.w) * w2 + bf2f(u3.w) * w3;
    }
    for (; e < end; e++) {
        int s = esrc[e];
        float wt = dinv[s] * di;
        ushort4 u = *(const ushort4*)&hw[(size_t)s * H + l * 4];
        a0 += bf2f(u.x) * wt; a1 += bf2f(u.y) * wt;
        a2 += bf2f(u.z) * wt; a3 += bf2f(u.w) * wt;
    }

    // self-loop + bias + relu + store
    ushort4 us = *(const ushort4*)&hw[(size_t)node * H + l * 4];
    float4 b4 = *(const float4*)&bias[l * 4];
    float dd = di * di;
    float v0 = a0 + bf2f(us.x) * dd + b4.x;
    float v1 = a1 + bf2f(us.y) * dd + b4.y;
    float v2 = a2 + bf2f(us.z) * dd + b4.z;
    float v3 = a3 + bf2f(us.w) * dd + b4.w;
    if (do_relu) {
        v0 = fmaxf(v0, 0.f); v1 = fmaxf(v1, 0.f);
        v2 = fmaxf(v2, 0.f); v3 = fmaxf(v3, 0.f);
    }
    ushort4 o;
    o.x = f2bf(v0); o.y = f2bf(v1); o.z = f2bf(v2); o.w = f2bf(v3);
    *(ushort4*)&hout[(size_t)node * H + l * 4] = o;
}

// ---------------- mean pool ----------------
__global__ void pool_mean(const u16* __restrict__ h, const int* __restrict__ goff,
                          float* __restrict__ pooled) {
    int g = blockIdx.x;
    int j = threadIdx.x;
    int beg = goff[g], end = goff[g + 1];
    float acc = 0.f;
    for (int i = beg; i < end; i++) acc += bf2f(h[(size_t)i * H + j]);
    float c = (float)(end - beg);
    pooled[g * H + j] = acc / fmaxf(c, 1.f);
}

// ---------------- MLP ----------------
__global__ void mlp1(const float* __restrict__ pooled, const float* __restrict__ Wm1,
                     const float* __restrict__ bm1, float* __restrict__ hidden) {
    __shared__ float p[H];
    int g = blockIdx.x, t = threadIdx.x;
    p[t] = pooled[g * H + t];
    __syncthreads();
#pragma unroll
    for (int rep = 0; rep < 2; rep++) {
        int o = rep * 256 + t;
        float acc = bm1[o];
        for (int k = 0; k < H; k++) acc += p[k] * Wm1[(size_t)k * NHID + o];
        hidden[g * NHID + o] = fmaxf(acc, 0.f);
    }
}

__global__ void mlp2(const float* __restrict__ hidden, const float* __restrict__ Wm2,
                     const float* __restrict__ bm2, float* __restrict__ out) {
    __shared__ float p[NHID];
    int g = blockIdx.x, t = threadIdx.x;
    p[t] = hidden[g * NHID + t];
    p[t + 256] = hidden[g * NHID + t + 256];
    __syncthreads();
    float acc = bm2[t];
    for (int k = 0; k < NHID; k++) acc += p[k] * Wm2[(size_t)k * NOUT + t];
    out[g * NOUT + t] = acc;
}

// ---------------- launch ----------------
extern "C" void kernel_launch(void* const* d_in, const int* in_sizes, int n_in,
                              void* d_out, int out_size, void* d_ws, size_t ws_size,
                              hipStream_t stream) {
    const float* x   = (const float*)d_in[0];
    const int*   src = (const int*)d_in[1];
    const int*   dst = (const int*)d_in[2];
    const int*   bat = (const int*)d_in[3];
    const float* W1  = (const float*)d_in[4];  const float* b1  = (const float*)d_in[5];
    const float* W2  = (const float*)d_in[6];  const float* b2  = (const float*)d_in[7];
    const float* W3  = (const float*)d_in[8];  const float* b3  = (const float*)d_in[9];
    const float* Wm1 = (const float*)d_in[10]; const float* bm1 = (const float*)d_in[11];
    const float* Wm2 = (const float*)d_in[12]; const float* bm2 = (const float*)d_in[13];
    float* out = (float*)d_out;

    char* p = (char*)d_ws;
    auto carve = [&](size_t bytes) -> void* {
        void* r = (void*)p;
        p += (bytes + 511) & ~(size_t)511;
        return r;
    };
    u16*   hw      = (u16*)  carve((size_t)N_NODES * H * 2);
    u16*   h       = (u16*)  carve((size_t)N_NODES * H * 2);
    float* dinv    = (float*)carve((size_t)N_NODES * 4);
    int*   degc    = (int*)  carve((size_t)N_NODES * 4);
    int*   rowp    = (int*)  carve((size_t)(N_NODES + 1) * 4);
    int*   cur     = (int*)  carve((size_t)N_NODES * 4);
    int*   esrc    = (int*)  carve((size_t)N_EDGES * 4);
    int*   partial = (int*)  carve(4096);
    int*   goff    = (int*)  carve((size_t)(G_GR + 1) * 4);
    float* pooled  = (float*)carve((size_t)G_GR * H * 4);
    float* hidden  = (float*)carve((size_t)G_GR * NHID * 4);
    u16*   Wt1_hi  = (u16*)  carve((size_t)F_IN * H * 2);
    u16*   Wt1_lo  = (u16*)  carve((size_t)F_IN * H * 2);
    u16*   Wt2_hi  = (u16*)  carve((size_t)H * H * 2);
    u16*   Wt2_lo  = (u16*)  carve((size_t)H * H * 2);
    u16*   Wt3_hi  = (u16*)  carve((size_t)H * H * 2);
    u16*   Wt3_lo  = (u16*)  carve((size_t)H * H * 2);
    // x_hi/x_lo alias the h buffer (dead until aggregate L1 writes it, after L1 GEMM reads these)
    u16*   x_hi    = h;
    u16*   x_lo    = h + (size_t)N_NODES * F_IN;

    const int NB = (N_NODES + 255) / 256;
    const int EB = (N_EDGES + 255) / 256;

    hipMemsetAsync(degc, 0, (size_t)N_NODES * 4, stream);
    count_deg<<<EB, 256, 0, stream>>>(dst, degc);
    compute_dinv<<<NB, 256, 0, stream>>>(degc, dinv);
    scan_partial<<<NB, 256, 0, stream>>>(degc, partial);
    scan_offsets<<<1, 512, 0, stream>>>(partial, NB, rowp);
    scan_final<<<NB, 256, 0, stream>>>(degc, partial, rowp);
    init_cursor<<<NB, 256, 0, stream>>>(rowp, cur);
    scatter_edges<<<EB, 256, 0, stream>>>(src, dst, cur, esrc);
    graph_offsets<<<2, 256, 0, stream>>>(bat, goff);

    split_f32<<<(N_NODES * F_IN + 255) / 256, 256, 0, stream>>>(x, x_hi, x_lo, N_NODES * F_IN);
    transpose_split<<<(F_IN * H + 255) / 256, 256, 0, stream>>>(W1, Wt1_hi, Wt1_lo, F_IN, H);
    transpose_split<<<(H * H + 255) / 256, 256, 0, stream>>>(W2, Wt2_hi, Wt2_lo, H, H);
    transpose_split<<<(H * H + 255) / 256, 256, 0, stream>>>(W3, Wt3_hi, Wt3_lo, H, H);

    dim3 ggrid((N_NODES + 127) / 128, 2);
    const int AGG_B = N_NODES / 4;   // 25000 blocks, wave per node

    // layer 1 (A split: x_hi + x_lo)
    gemm_mfma<F_IN, true><<<ggrid, 256, 0, stream>>>(x_hi, x_lo, Wt1_hi, Wt1_lo, hw, N_NODES);
    gcn_aggregate<<<AGG_B, 256, 0, stream>>>(hw, rowp, esrc, dinv, b1, h, 1);
    // layer 2
    gemm_mfma<H, false><<<ggrid, 256, 0, stream>>>(h, h, Wt2_hi, Wt2_lo, hw, N_NODES);
    gcn_aggregate<<<AGG_B, 256, 0, stream>>>(hw, rowp, esrc, dinv, b2, h, 1);
    // layer 3
    gemm_mfma<H, false><<<ggrid, 256, 0, stream>>>(h, h, Wt3_hi, Wt3_lo, hw, N_NODES);
    gcn_aggregate<<<AGG_B, 256, 0, stream>>>(hw, rowp, esrc, dinv, b3, h, 0);

    pool_mean<<<G_GR, 256, 0, stream>>>(h, goff, pooled);
    mlp1<<<G_GR, 256, 0, stream>>>(pooled, Wm1, bm1, hidden);
    mlp2<<<G_GR, 256, 0, stream>>>(hidden, Wm2, bm2, out);
}

// Round 5
// 964.427 us; speedup vs baseline: 1.9041x; 1.0060x over previous
//
#include <hip/hip_runtime.h>
#include <hip/hip_bf16.h>

#define N_NODES 100000
#define N_EDGES 1600000
#define F_IN    128
#define H       256
#define NHID    512
#define NOUT    256
#define G_GR    256

typedef unsigned short u16;
typedef __attribute__((ext_vector_type(8))) short s16x8;          // 8 bf16 (MFMA operand)
typedef __attribute__((ext_vector_type(8))) unsigned short u16x8; // 16B load/store
typedef __attribute__((ext_vector_type(4))) float f32x4;          // MFMA acc

__device__ __forceinline__ float bf2f(u16 u) {
    union { unsigned int i; float f; } v; v.i = ((unsigned int)u) << 16; return v.f;
}
__device__ __forceinline__ u16 f2bf(float f) {
    union { float f; unsigned int i; } v; v.f = f;
    unsigned int x = v.i;
    x += 0x7fffu + ((x >> 16) & 1u);   // round-to-nearest-even
    return (u16)(x >> 16);
}

// ---------------- fused prep: count_deg | split_f32(x) | transpose_split(W1,W2,W3) | graph_offsets ----------------
#define CD_BLKS   ((N_EDGES + 255) / 256)            // 6250
#define SX_BLKS   ((N_NODES * F_IN) / 256)           // 50000
#define T1_BLKS   ((F_IN * H) / 256)                 // 128
#define T2_BLKS   ((H * H) / 256)                    // 256
#define PREP_BLKS (CD_BLKS + SX_BLKS + T1_BLKS + 2 * T2_BLKS + 2)

__device__ __forceinline__ void transpose_split_body(const float* __restrict__ W,
        u16* __restrict__ thi, u16* __restrict__ tlo, int K, int N, int id) {
    int n = id / K, k = id - n * K;
    float f = W[(size_t)k * N + n];
    u16 h = f2bf(f);
    thi[id] = h;
    tlo[id] = f2bf(f - bf2f(h));
}

__global__ __launch_bounds__(256) void prep_fused(
        const int* __restrict__ dst, int* __restrict__ degc,
        const float* __restrict__ x, u16* __restrict__ x_hi, u16* __restrict__ x_lo,
        const float* __restrict__ W1, u16* __restrict__ t1h, u16* __restrict__ t1l,
        const float* __restrict__ W2, u16* __restrict__ t2h, u16* __restrict__ t2l,
        const float* __restrict__ W3, u16* __restrict__ t3h, u16* __restrict__ t3l,
        const int* __restrict__ batch, int* __restrict__ goff) {
    int bid = blockIdx.x;
    if (bid < CD_BLKS) {
        int e = bid * 256 + threadIdx.x;
        if (e < N_EDGES) atomicAdd(&degc[dst[e]], 1);
        return;
    }
    bid -= CD_BLKS;
    if (bid < SX_BLKS) {
        int i = bid * 256 + threadIdx.x;
        float f = x[i];
        u16 h = f2bf(f);
        x_hi[i] = h;
        x_lo[i] = f2bf(f - bf2f(h));
        return;
    }
    bid -= SX_BLKS;
    if (bid < T1_BLKS) {
        transpose_split_body(W1, t1h, t1l, F_IN, H, bid * 256 + threadIdx.x);
        return;
    }
    bid -= T1_BLKS;
    if (bid < T2_BLKS) {
        transpose_split_body(W2, t2h, t2l, H, H, bid * 256 + threadIdx.x);
        return;
    }
    bid -= T2_BLKS;
    if (bid < T2_BLKS) {
        transpose_split_body(W3, t3h, t3l, H, H, bid * 256 + threadIdx.x);
        return;
    }
    bid -= T2_BLKS;
    {   // graph offsets: lower_bound on sorted batch
        int g = bid * 256 + threadIdx.x;
        if (g > G_GR) return;
        int lo = 0, hi = N_NODES;
        while (lo < hi) {
            int mid = (lo + hi) >> 1;
            if (batch[mid] < g) lo = mid + 1; else hi = mid;
        }
        goff[g] = lo;
    }
}

// ---------------- scan (CSR rowp) ----------------
__global__ void scan_partial(const int* __restrict__ cnt, int* __restrict__ partial) {
    __shared__ int s[256];
    int t = threadIdx.x;
    int i = blockIdx.x * 256 + t;
    int v = (i < N_NODES) ? cnt[i] : 0;
    s[t] = v; __syncthreads();
    for (int off = 128; off > 0; off >>= 1) {
        if (t < off) s[t] += s[t + off];
        __syncthreads();
    }
    if (t == 0) partial[blockIdx.x] = s[0];
}

__global__ void scan_offsets(int* __restrict__ partial, int nb, int* __restrict__ rowp) {
    __shared__ int s[512];
    int t = threadIdx.x;
    int orig = (t < nb) ? partial[t] : 0;
    s[t] = orig; __syncthreads();
    for (int off = 1; off < 512; off <<= 1) {
        int u = (t >= off) ? s[t - off] : 0;
        __syncthreads();
        s[t] += u;
        __syncthreads();
    }
    if (t < nb) partial[t] = s[t] - orig;
    if (t == 0) rowp[N_NODES] = N_EDGES;
}

// scan_final + cursor init + dinv, fused
__global__ void scan_final_dinv(const int* __restrict__ cnt, const int* __restrict__ partial,
                                int* __restrict__ rowp, int* __restrict__ cur,
                                float* __restrict__ dinv) {
    __shared__ int s[256];
    int t = threadIdx.x;
    int i = blockIdx.x * 256 + t;
    int v = (i < N_NODES) ? cnt[i] : 0;
    s[t] = v; __syncthreads();
    for (int off = 1; off < 256; off <<= 1) {
        int u = (t >= off) ? s[t - off] : 0;
        __syncthreads();
        s[t] += u;
        __syncthreads();
    }
    if (i < N_NODES) {
        int r = partial[blockIdx.x] + s[t] - v;
        rowp[i] = r;
        cur[i] = r;
        dinv[i] = rsqrtf(1.0f + (float)v);
    }
}

// ---------------- mega kernel: GEMM1 (MFMA, split A+W) blocks first, then edge scatter ----------------
#define GEMM1_BLKS (((N_NODES + 127) / 128) * 2)     // 782 * 2 = 1564
#define SCAT_BLKS  CD_BLKS                            // 6250

__global__ __launch_bounds__(256) void gemm1_scatter(
        const u16* __restrict__ Ahi, const u16* __restrict__ Alo,
        const u16* __restrict__ Bhi, const u16* __restrict__ Blo,
        u16* __restrict__ C,
        const int* __restrict__ src, const int* __restrict__ dst,
        int* __restrict__ cur, int* __restrict__ esrc) {
    __shared__ __align__(16) u16 sA[2 * 128 * 40];
    __shared__ __align__(16) u16 sB[2 * 128 * 40];
    const int K = F_IN, M = N_NODES;
    int bid = blockIdx.x;
    if (bid >= GEMM1_BLKS) {
        // ---- scatter branch ----
        int e = (bid - GEMM1_BLKS) * 256 + threadIdx.x;
        if (e < N_EDGES) {
            int d = dst[e];
            int pos = atomicAdd(&cur[d], 1);
            esrc[pos] = src[e];
        }
        return;
    }
    // ---- GEMM1 branch (K=128, split A) ----
    const int tid = threadIdx.x;
    const int w = tid >> 6, l = tid & 63;
    const int wm = (w & 1) * 64, wn = (w >> 1) * 64;
    const int bm = (bid >> 1) * 128, bn = (bid & 1) * 128;
    const int srow = tid >> 2;
    const int schunk = (tid & 3) * 8;
    const int lr = l & 15, lg = (l >> 4) * 8;

    f32x4 acc[4][4] = {};

    for (int k0 = 0; k0 < K; k0 += 32) {
        {
            int r0 = bm + srow, r1 = bm + srow + 64;
            u16x8 v0 = {}, v1 = {}, w0 = {}, w1 = {};
            if (r0 < M) {
                v0 = *(const u16x8*)&Ahi[(size_t)r0 * K + k0 + schunk];
                w0 = *(const u16x8*)&Alo[(size_t)r0 * K + k0 + schunk];
            }
            if (r1 < M) {
                v1 = *(const u16x8*)&Ahi[(size_t)r1 * K + k0 + schunk];
                w1 = *(const u16x8*)&Alo[(size_t)r1 * K + k0 + schunk];
            }
            *(u16x8*)&sA[srow * 40 + schunk] = v0;
            *(u16x8*)&sA[(srow + 64) * 40 + schunk] = v1;
            *(u16x8*)&sA[128 * 40 + srow * 40 + schunk] = w0;
            *(u16x8*)&sA[128 * 40 + (srow + 64) * 40 + schunk] = w1;
        }
        {
            int n0 = bn + srow, n1 = bn + srow + 64;
            *(u16x8*)&sB[srow * 40 + schunk] = *(const u16x8*)&Bhi[(size_t)n0 * K + k0 + schunk];
            *(u16x8*)&sB[(srow + 64) * 40 + schunk] = *(const u16x8*)&Bhi[(size_t)n1 * K + k0 + schunk];
            *(u16x8*)&sB[128 * 40 + srow * 40 + schunk] = *(const u16x8*)&Blo[(size_t)n0 * K + k0 + schunk];
            *(u16x8*)&sB[128 * 40 + (srow + 64) * 40 + schunk] = *(const u16x8*)&Blo[(size_t)n1 * K + k0 + schunk];
        }
        __syncthreads();

        s16x8 af[4], al[4], bh[4], bl[4];
#pragma unroll
        for (int i = 0; i < 4; i++) {
            af[i] = __builtin_bit_cast(s16x8, *(const u16x8*)&sA[(wm + i * 16 + lr) * 40 + lg]);
            al[i] = __builtin_bit_cast(s16x8, *(const u16x8*)&sA[128 * 40 + (wm + i * 16 + lr) * 40 + lg]);
        }
#pragma unroll
        for (int j = 0; j < 4; j++) {
            bh[j] = __builtin_bit_cast(s16x8, *(const u16x8*)&sB[(wn + j * 16 + lr) * 40 + lg]);
            bl[j] = __builtin_bit_cast(s16x8, *(const u16x8*)&sB[128 * 40 + (wn + j * 16 + lr) * 40 + lg]);
        }
#pragma unroll
        for (int i = 0; i < 4; i++) {
#pragma unroll
            for (int j = 0; j < 4; j++) {
                acc[i][j] = __builtin_amdgcn_mfma_f32_16x16x32_bf16(af[i], bh[j], acc[i][j], 0, 0, 0);
                acc[i][j] = __builtin_amdgcn_mfma_f32_16x16x32_bf16(af[i], bl[j], acc[i][j], 0, 0, 0);
                acc[i][j] = __builtin_amdgcn_mfma_f32_16x16x32_bf16(al[i], bh[j], acc[i][j], 0, 0, 0);
            }
        }
        __syncthreads();
    }

    const int lq = (l >> 4) * 4;
#pragma unroll
    for (int i = 0; i < 4; i++) {
#pragma unroll
        for (int r0 = 0; r0 < 4; r0++) {
            int row = bm + wm + i * 16 + lq + r0;
            if (row < M) {
#pragma unroll
                for (int j = 0; j < 4; j++)
                    C[(size_t)row * H + bn + wn + j * 16 + lr] = f2bf(acc[i][j][r0]);
            }
        }
    }
}

// ---------------- standalone MFMA GEMM (layers 2,3: bf16 A, hi+lo W) ----------------
template<int K>
__global__ __launch_bounds__(256) void gemm_mfma(
        const u16* __restrict__ A,
        const u16* __restrict__ Bhi, const u16* __restrict__ Blo,
        u16* __restrict__ C, int M) {
    __shared__ __align__(16) u16 sA[128 * 40];
    __shared__ __align__(16) u16 sB[2 * 128 * 40];
    const int tid = threadIdx.x;
    const int w = tid >> 6, l = tid & 63;
    const int wm = (w & 1) * 64, wn = (w >> 1) * 64;
    const int bm = blockIdx.x * 128, bn = blockIdx.y * 128;
    const int srow = tid >> 2;
    const int schunk = (tid & 3) * 8;
    const int lr = l & 15, lg = (l >> 4) * 8;

    f32x4 acc[4][4] = {};

    for (int k0 = 0; k0 < K; k0 += 32) {
        {
            int r0 = bm + srow, r1 = bm + srow + 64;
            u16x8 v0 = {}, v1 = {};
            if (r0 < M) v0 = *(const u16x8*)&A[(size_t)r0 * K + k0 + schunk];
            if (r1 < M) v1 = *(const u16x8*)&A[(size_t)r1 * K + k0 + schunk];
            *(u16x8*)&sA[srow * 40 + schunk] = v0;
            *(u16x8*)&sA[(srow + 64) * 40 + schunk] = v1;
        }
        {
            int n0 = bn + srow, n1 = bn + srow + 64;
            *(u16x8*)&sB[srow * 40 + schunk] = *(const u16x8*)&Bhi[(size_t)n0 * K + k0 + schunk];
            *(u16x8*)&sB[(srow + 64) * 40 + schunk] = *(const u16x8*)&Bhi[(size_t)n1 * K + k0 + schunk];
            *(u16x8*)&sB[128 * 40 + srow * 40 + schunk] = *(const u16x8*)&Blo[(size_t)n0 * K + k0 + schunk];
            *(u16x8*)&sB[128 * 40 + (srow + 64) * 40 + schunk] = *(const u16x8*)&Blo[(size_t)n1 * K + k0 + schunk];
        }
        __syncthreads();

        s16x8 af[4], bh[4], bl[4];
#pragma unroll
        for (int i = 0; i < 4; i++)
            af[i] = __builtin_bit_cast(s16x8, *(const u16x8*)&sA[(wm + i * 16 + lr) * 40 + lg]);
#pragma unroll
        for (int j = 0; j < 4; j++) {
            bh[j] = __builtin_bit_cast(s16x8, *(const u16x8*)&sB[(wn + j * 16 + lr) * 40 + lg]);
            bl[j] = __builtin_bit_cast(s16x8, *(const u16x8*)&sB[128 * 40 + (wn + j * 16 + lr) * 40 + lg]);
        }
#pragma unroll
        for (int i = 0; i < 4; i++) {
#pragma unroll
            for (int j = 0; j < 4; j++) {
                acc[i][j] = __builtin_amdgcn_mfma_f32_16x16x32_bf16(af[i], bh[j], acc[i][j], 0, 0, 0);
                acc[i][j] = __builtin_amdgcn_mfma_f32_16x16x32_bf16(af[i], bl[j], acc[i][j], 0, 0, 0);
            }
        }
        __syncthreads();
    }

    const int lq = (l >> 4) * 4;
#pragma unroll
    for (int i = 0; i < 4; i++) {
#pragma unroll
        for (int r0 = 0; r0 < 4; r0++) {
            int row = bm + wm + i * 16 + lq + r0;
            if (row < M) {
#pragma unroll
                for (int j = 0; j < 4; j++)
                    C[(size_t)row * H + bn + wn + j * 16 + lr] = f2bf(acc[i][j][r0]);
            }
        }
    }
}

// ---------------- GCN aggregation: wave per node, 8-wide edge pipeline ----------------
__global__ __launch_bounds__(256) void gcn_aggregate(
        const u16* __restrict__ hw, const int* __restrict__ rowp,
        const int* __restrict__ esrc, const float* __restrict__ dinv,
        const float* __restrict__ bias, u16* __restrict__ hout, int do_relu) {
    int node = blockIdx.x * 4 + (threadIdx.x >> 6);
    int l = threadIdx.x & 63;
    float di = dinv[node];
    int beg = rowp[node], end = rowp[node + 1];

    float a0 = 0.f, a1 = 0.f, a2 = 0.f, a3 = 0.f;
    int e = beg;
    for (; e + 8 <= end; e += 8) {
        int s[8]; float wt[8];
#pragma unroll
        for (int q = 0; q < 8; q++) s[q] = esrc[e + q];
#pragma unroll
        for (int q = 0; q < 8; q++) wt[q] = dinv[s[q]] * di;
#pragma unroll
        for (int q = 0; q < 8; q++) {
            ushort4 u = *(const ushort4*)&hw[(size_t)s[q] * H + l * 4];
            a0 += bf2f(u.x) * wt[q];
            a1 += bf2f(u.y) * wt[q];
            a2 += bf2f(u.z) * wt[q];
            a3 += bf2f(u.w) * wt[q];
        }
    }
    for (; e < end; e++) {
        int s = esrc[e];
        float wt = dinv[s] * di;
        ushort4 u = *(const ushort4*)&hw[(size_t)s * H + l * 4];
        a0 += bf2f(u.x) * wt; a1 += bf2f(u.y) * wt;
        a2 += bf2f(u.z) * wt; a3 += bf2f(u.w) * wt;
    }

    ushort4 us = *(const ushort4*)&hw[(size_t)node * H + l * 4];
    float4 b4 = *(const float4*)&bias[l * 4];
    float dd = di * di;
    float v0 = a0 + bf2f(us.x) * dd + b4.x;
    float v1 = a1 + bf2f(us.y) * dd + b4.y;
    float v2 = a2 + bf2f(us.z) * dd + b4.z;
    float v3 = a3 + bf2f(us.w) * dd + b4.w;
    if (do_relu) {
        v0 = fmaxf(v0, 0.f); v1 = fmaxf(v1, 0.f);
        v2 = fmaxf(v2, 0.f); v3 = fmaxf(v3, 0.f);
    }
    ushort4 o;
    o.x = f2bf(v0); o.y = f2bf(v1); o.z = f2bf(v2); o.w = f2bf(v3);
    *(ushort4*)&hout[(size_t)node * H + l * 4] = o;
}

// ---------------- fused tail: mean-pool -> mlp1 -> mlp2, one block per graph ----------------
__global__ __launch_bounds__(256) void pool_mlp(
        const u16* __restrict__ h, const int* __restrict__ goff,
        const float* __restrict__ Wm1, const float* __restrict__ bm1,
        const float* __restrict__ Wm2, const float* __restrict__ bm2,
        float* __restrict__ out) {
    __shared__ float p[H];
    __shared__ float hid[NHID];
    int g = blockIdx.x, t = threadIdx.x;
    int beg = goff[g], end = goff[g + 1];
    float acc = 0.f;
    for (int i = beg; i < end; i++) acc += bf2f(h[(size_t)i * H + t]);
    p[t] = acc / fmaxf((float)(end - beg), 1.f);
    __syncthreads();
#pragma unroll
    for (int rep = 0; rep < 2; rep++) {
        int o = rep * 256 + t;
        float a = bm1[o];
        for (int k = 0; k < H; k++) a += p[k] * Wm1[(size_t)k * NHID + o];
        hid[o] = fmaxf(a, 0.f);
    }
    __syncthreads();
    float a = bm2[t];
    for (int k = 0; k < NHID; k++) a += hid[k] * Wm2[(size_t)k * NOUT + t];
    out[g * NOUT + t] = a;
}

// ---------------- launch ----------------
extern "C" void kernel_launch(void* const* d_in, const int* in_sizes, int n_in,
                              void* d_out, int out_size, void* d_ws, size_t ws_size,
                              hipStream_t stream) {
    const float* x   = (const float*)d_in[0];
    const int*   src = (const int*)d_in[1];
    const int*   dst = (const int*)d_in[2];
    const int*   bat = (const int*)d_in[3];
    const float* W1  = (const float*)d_in[4];  const float* b1  = (const float*)d_in[5];
    const float* W2  = (const float*)d_in[6];  const float* b2  = (const float*)d_in[7];
    const float* W3  = (const float*)d_in[8];  const float* b3  = (const float*)d_in[9];
    const float* Wm1 = (const float*)d_in[10]; const float* bm1 = (const float*)d_in[11];
    const float* Wm2 = (const float*)d_in[12]; const float* bm2 = (const float*)d_in[13];
    float* out = (float*)d_out;

    char* p = (char*)d_ws;
    auto carve = [&](size_t bytes) -> void* {
        void* r = (void*)p;
        p += (bytes + 511) & ~(size_t)511;
        return r;
    };
    u16*   hw      = (u16*)  carve((size_t)N_NODES * H * 2);
    u16*   h       = (u16*)  carve((size_t)N_NODES * H * 2);
    float* dinv    = (float*)carve((size_t)N_NODES * 4);
    int*   degc    = (int*)  carve((size_t)N_NODES * 4);
    int*   rowp    = (int*)  carve((size_t)(N_NODES + 1) * 4);
    int*   cur     = (int*)  carve((size_t)N_NODES * 4);
    int*   esrc    = (int*)  carve((size_t)N_EDGES * 4);
    int*   partial = (int*)  carve(4096);
    int*   goff    = (int*)  carve((size_t)(G_GR + 1) * 4);
    u16*   Wt1_hi  = (u16*)  carve((size_t)F_IN * H * 2);
    u16*   Wt1_lo  = (u16*)  carve((size_t)F_IN * H * 2);
    u16*   Wt2_hi  = (u16*)  carve((size_t)H * H * 2);
    u16*   Wt2_lo  = (u16*)  carve((size_t)H * H * 2);
    u16*   Wt3_hi  = (u16*)  carve((size_t)H * H * 2);
    u16*   Wt3_lo  = (u16*)  carve((size_t)H * H * 2);
    // x_hi/x_lo alias the h buffer (dead until aggregate L1 writes it, after L1 GEMM reads these)
    u16*   x_hi    = h;
    u16*   x_lo    = h + (size_t)N_NODES * F_IN;

    const int NB = (N_NODES + 255) / 256;

    hipMemsetAsync(degc, 0, (size_t)N_NODES * 4, stream);
    prep_fused<<<PREP_BLKS, 256, 0, stream>>>(dst, degc, x, x_hi, x_lo,
                                              W1, Wt1_hi, Wt1_lo,
                                              W2, Wt2_hi, Wt2_lo,
                                              W3, Wt3_hi, Wt3_lo,
                                              bat, goff);
    scan_partial<<<NB, 256, 0, stream>>>(degc, partial);
    scan_offsets<<<1, 512, 0, stream>>>(partial, NB, rowp);
    scan_final_dinv<<<NB, 256, 0, stream>>>(degc, partial, rowp, cur, dinv);

    dim3 ggrid((N_NODES + 127) / 128, 2);
    const int AGG_B = N_NODES / 4;

    // layer 1 GEMM overlapped with edge scatter (independent work)
    gemm1_scatter<<<GEMM1_BLKS + SCAT_BLKS, 256, 0, stream>>>(
        x_hi, x_lo, Wt1_hi, Wt1_lo, hw, src, dst, cur, esrc);
    gcn_aggregate<<<AGG_B, 256, 0, stream>>>(hw, rowp, esrc, dinv, b1, h, 1);
    // layer 2
    gemm_mfma<H><<<ggrid, 256, 0, stream>>>(h, Wt2_hi, Wt2_lo, hw, N_NODES);
    gcn_aggregate<<<AGG_B, 256, 0, stream>>>(hw, rowp, esrc, dinv, b2, h, 1);
    // layer 3
    gemm_mfma<H><<<ggrid, 256, 0, stream>>>(h, Wt3_hi, Wt3_lo, hw, N_NODES);
    gcn_aggregate<<<AGG_B, 256, 0, stream>>>(hw, rowp, esrc, dinv, b3, h, 0);

    pool_mlp<<<G_GR, 256, 0, stream>>>(h, goff, Wm1, bm1, Wm2, bm2, out);
}

// Round 6
// 833.229 us; speedup vs baseline: 2.2039x; 1.1575x over previous
//
#include <hip/hip_runtime.h>
#include <hip/hip_bf16.h>

#define N_NODES 100000
#define N_EDGES 1600000
#define F_IN    128
#define H       256
#define NHID    512
#define NOUT    256
#define G_GR    256

typedef unsigned short u16;
typedef __attribute__((ext_vector_type(8))) short s16x8;
typedef __attribute__((ext_vector_type(8))) unsigned short u16x8;
typedef __attribute__((ext_vector_type(4))) float f32x4;

__device__ __forceinline__ float bf2f(u16 u) {
    union { unsigned int i; float f; } v; v.i = ((unsigned int)u) << 16; return v.f;
}
__device__ __forceinline__ u16 f2bf(float f) {
    union { float f; unsigned int i; } v; v.f = f;
    unsigned int x = v.i;
    x += 0x7fffu + ((x >> 16) & 1u);
    return (u16)(x >> 16);
}

// ---------------- graph prep ----------------

__global__ void count_deg(const int* __restrict__ dst, int* __restrict__ degc) {
    int e = blockIdx.x * 256 + threadIdx.x;
    if (e < N_EDGES) atomicAdd(&degc[dst[e]], 1);
}

__global__ void scan_partial(const int* __restrict__ cnt, int* __restrict__ partial) {
    __shared__ int s[256];
    int t = threadIdx.x;
    int i = blockIdx.x * 256 + t;
    int v = (i < N_NODES) ? cnt[i] : 0;
    s[t] = v; __syncthreads();
    for (int off = 128; off > 0; off >>= 1) {
        if (t < off) s[t] += s[t + off];
        __syncthreads();
    }
    if (t == 0) partial[blockIdx.x] = s[0];
}

__global__ void scan_offsets(int* __restrict__ partial, int nb, int* __restrict__ rowp) {
    __shared__ int s[512];
    int t = threadIdx.x;
    int orig = (t < nb) ? partial[t] : 0;
    s[t] = orig; __syncthreads();
    for (int off = 1; off < 512; off <<= 1) {
        int u = (t >= off) ? s[t - off] : 0;
        __syncthreads();
        s[t] += u;
        __syncthreads();
    }
    if (t < nb) partial[t] = s[t] - orig;
    if (t == 0) rowp[N_NODES] = N_EDGES;
}

__global__ void scan_final_dinv(const int* __restrict__ cnt, const int* __restrict__ partial,
                                int* __restrict__ rowp, int* __restrict__ cur,
                                float* __restrict__ dinv) {
    __shared__ int s[256];
    int t = threadIdx.x;
    int i = blockIdx.x * 256 + t;
    int v = (i < N_NODES) ? cnt[i] : 0;
    s[t] = v; __syncthreads();
    for (int off = 1; off < 256; off <<= 1) {
        int u = (t >= off) ? s[t - off] : 0;
        __syncthreads();
        s[t] += u;
        __syncthreads();
    }
    if (i < N_NODES) {
        int r = partial[blockIdx.x] + s[t] - v;
        rowp[i] = r;
        cur[i] = r;
        dinv[i] = rsqrtf(1.0f + (float)v);
    }
}

// ---------------- fused: edge scatter (LDS-free, high occupancy) + split_x + W transposes + goff ----------------
#define SCAT_BLKS 1563                       // 4 edges/thread: 1563*1024 >= 1.6M
#define SPX_BLKS  ((N_NODES * F_IN) / 1024)  // 12500 (4 floats/thread)
#define T1_BLKS   ((F_IN * H) / 256)         // 128
#define T2_BLKS   ((H * H) / 256)            // 256
#define PREP2_BLKS (SCAT_BLKS + SPX_BLKS + T1_BLKS + T2_BLKS + 2)

__device__ __forceinline__ void transpose_split_body(const float* __restrict__ W,
        u16* __restrict__ thi, u16* __restrict__ tlo, int K, int N, int id) {
    int n = id / K, k = id - n * K;
    float f = W[(size_t)k * N + n];
    u16 h = f2bf(f);
    thi[id] = h;
    tlo[id] = f2bf(f - bf2f(h));
}

__global__ __launch_bounds__(256) void scatter_prep_fused(
        const int* __restrict__ src, const int* __restrict__ dst,
        int* __restrict__ cur, int* __restrict__ esrc,
        const float* __restrict__ x, u16* __restrict__ x_bf,
        const float* __restrict__ W1, u16* __restrict__ t1h, u16* __restrict__ t1l,
        const float* __restrict__ W2, u16* __restrict__ t2h, u16* __restrict__ t2l,
        const int* __restrict__ batch, int* __restrict__ goff) {
    int bid = blockIdx.x;
    if (bid < SCAT_BLKS) {
        int base = bid * 1024 + threadIdx.x;
#pragma unroll
        for (int q = 0; q < 4; q++) {
            int e = base + q * 256;
            if (e < N_EDGES) {
                int d = dst[e];
                int pos = atomicAdd(&cur[d], 1);
                esrc[pos] = src[e];
            }
        }
        return;
    }
    bid -= SCAT_BLKS;
    if (bid < SPX_BLKS) {
        int idx = bid * 256 + threadIdx.x;      // 4 floats per thread
        float4 f = *(const float4*)&x[(size_t)idx * 4];
        ushort4 o;
        o.x = f2bf(f.x); o.y = f2bf(f.y); o.z = f2bf(f.z); o.w = f2bf(f.w);
        *(ushort4*)&x_bf[(size_t)idx * 4] = o;
        return;
    }
    bid -= SPX_BLKS;
    if (bid < T1_BLKS) {
        transpose_split_body(W1, t1h, t1l, F_IN, H, bid * 256 + threadIdx.x);
        return;
    }
    bid -= T1_BLKS;
    if (bid < T2_BLKS) {
        transpose_split_body(W2, t2h, t2l, H, H, bid * 256 + threadIdx.x);
        return;
    }
    bid -= T2_BLKS;
    {
        int g = bid * 256 + threadIdx.x;
        if (g > G_GR) return;
        int lo = 0, hi = N_NODES;
        while (lo < hi) {
            int mid = (lo + hi) >> 1;
            if (batch[mid] < g) lo = mid + 1; else hi = mid;
        }
        goff[g] = lo;
    }
}

// ---------------- pure aggregation: out[i] = sum_j w_ij in[src_j] + dinv_i^2 in[i] ----------------
// wave per node, 8-wide edge pipeline. FW=128: ushort2/lane; FW=256: ushort4/lane.

__global__ __launch_bounds__(256) void gcn_agg128(
        const u16* __restrict__ in, const int* __restrict__ rowp,
        const int* __restrict__ esrc, const float* __restrict__ dinv,
        u16* __restrict__ outp) {
    int node = blockIdx.x * 4 + (threadIdx.x >> 6);
    int l = threadIdx.x & 63;
    float di = dinv[node];
    int beg = rowp[node], end = rowp[node + 1];
    float a0 = 0.f, a1 = 0.f;
    int e = beg;
    for (; e + 8 <= end; e += 8) {
        int s[8]; float wt[8];
#pragma unroll
        for (int q = 0; q < 8; q++) s[q] = esrc[e + q];
#pragma unroll
        for (int q = 0; q < 8; q++) wt[q] = dinv[s[q]] * di;
#pragma unroll
        for (int q = 0; q < 8; q++) {
            ushort2 u = *(const ushort2*)&in[(size_t)s[q] * F_IN + l * 2];
            a0 += bf2f(u.x) * wt[q];
            a1 += bf2f(u.y) * wt[q];
        }
    }
    for (; e < end; e++) {
        int s = esrc[e];
        float wt = dinv[s] * di;
        ushort2 u = *(const ushort2*)&in[(size_t)s * F_IN + l * 2];
        a0 += bf2f(u.x) * wt; a1 += bf2f(u.y) * wt;
    }
    ushort2 us = *(const ushort2*)&in[(size_t)node * F_IN + l * 2];
    float dd = di * di;
    ushort2 o;
    o.x = f2bf(a0 + bf2f(us.x) * dd);
    o.y = f2bf(a1 + bf2f(us.y) * dd);
    *(ushort2*)&outp[(size_t)node * F_IN + l * 2] = o;
}

__global__ __launch_bounds__(256) void gcn_agg256(
        const u16* __restrict__ in, const int* __restrict__ rowp,
        const int* __restrict__ esrc, const float* __restrict__ dinv,
        u16* __restrict__ outp) {
    int node = blockIdx.x * 4 + (threadIdx.x >> 6);
    int l = threadIdx.x & 63;
    float di = dinv[node];
    int beg = rowp[node], end = rowp[node + 1];
    float a0 = 0.f, a1 = 0.f, a2 = 0.f, a3 = 0.f;
    int e = beg;
    for (; e + 8 <= end; e += 8) {
        int s[8]; float wt[8];
#pragma unroll
        for (int q = 0; q < 8; q++) s[q] = esrc[e + q];
#pragma unroll
        for (int q = 0; q < 8; q++) wt[q] = dinv[s[q]] * di;
#pragma unroll
        for (int q = 0; q < 8; q++) {
            ushort4 u = *(const ushort4*)&in[(size_t)s[q] * H + l * 4];
            a0 += bf2f(u.x) * wt[q];
            a1 += bf2f(u.y) * wt[q];
            a2 += bf2f(u.z) * wt[q];
            a3 += bf2f(u.w) * wt[q];
        }
    }
    for (; e < end; e++) {
        int s = esrc[e];
        float wt = dinv[s] * di;
        ushort4 u = *(const ushort4*)&in[(size_t)s * H + l * 4];
        a0 += bf2f(u.x) * wt; a1 += bf2f(u.y) * wt;
        a2 += bf2f(u.z) * wt; a3 += bf2f(u.w) * wt;
    }
    ushort4 us = *(const ushort4*)&in[(size_t)node * H + l * 4];
    float dd = di * di;
    ushort4 o;
    o.x = f2bf(a0 + bf2f(us.x) * dd);
    o.y = f2bf(a1 + bf2f(us.y) * dd);
    o.z = f2bf(a2 + bf2f(us.z) * dd);
    o.w = f2bf(a3 + bf2f(us.w) * dd);
    *(ushort4*)&outp[(size_t)node * H + l * 4] = o;
}

// ---------------- MFMA GEMM with bias(+relu) epilogue: C = A[MxK] @ Wt[256xK]^T ----------------
template<int K, bool RELU>
__global__ __launch_bounds__(256) void gemm_bias(
        const u16* __restrict__ A,
        const u16* __restrict__ Bhi, const u16* __restrict__ Blo,
        const float* __restrict__ bias, u16* __restrict__ C, int M) {
    __shared__ __align__(16) u16 sA[128 * 40];
    __shared__ __align__(16) u16 sB[2 * 128 * 40];
    const int tid = threadIdx.x;
    const int w = tid >> 6, l = tid & 63;
    const int wm = (w & 1) * 64, wn = (w >> 1) * 64;
    const int bm = blockIdx.x * 128, bn = blockIdx.y * 128;
    const int srow = tid >> 2;
    const int schunk = (tid & 3) * 8;
    const int lr = l & 15, lg = (l >> 4) * 8;

    f32x4 acc[4][4] = {};

    for (int k0 = 0; k0 < K; k0 += 32) {
        {
            int r0 = bm + srow, r1 = bm + srow + 64;
            u16x8 v0 = {}, v1 = {};
            if (r0 < M) v0 = *(const u16x8*)&A[(size_t)r0 * K + k0 + schunk];
            if (r1 < M) v1 = *(const u16x8*)&A[(size_t)r1 * K + k0 + schunk];
            *(u16x8*)&sA[srow * 40 + schunk] = v0;
            *(u16x8*)&sA[(srow + 64) * 40 + schunk] = v1;
        }
        {
            int n0 = bn + srow, n1 = bn + srow + 64;
            *(u16x8*)&sB[srow * 40 + schunk] = *(const u16x8*)&Bhi[(size_t)n0 * K + k0 + schunk];
            *(u16x8*)&sB[(srow + 64) * 40 + schunk] = *(const u16x8*)&Bhi[(size_t)n1 * K + k0 + schunk];
            *(u16x8*)&sB[128 * 40 + srow * 40 + schunk] = *(const u16x8*)&Blo[(size_t)n0 * K + k0 + schunk];
            *(u16x8*)&sB[128 * 40 + (srow + 64) * 40 + schunk] = *(const u16x8*)&Blo[(size_t)n1 * K + k0 + schunk];
        }
        __syncthreads();

        s16x8 af[4], bh[4], bl[4];
#pragma unroll
        for (int i = 0; i < 4; i++)
            af[i] = __builtin_bit_cast(s16x8, *(const u16x8*)&sA[(wm + i * 16 + lr) * 40 + lg]);
#pragma unroll
        for (int j = 0; j < 4; j++) {
            bh[j] = __builtin_bit_cast(s16x8, *(const u16x8*)&sB[(wn + j * 16 + lr) * 40 + lg]);
            bl[j] = __builtin_bit_cast(s16x8, *(const u16x8*)&sB[128 * 40 + (wn + j * 16 + lr) * 40 + lg]);
        }
#pragma unroll
        for (int i = 0; i < 4; i++) {
#pragma unroll
            for (int j = 0; j < 4; j++) {
                acc[i][j] = __builtin_amdgcn_mfma_f32_16x16x32_bf16(af[i], bh[j], acc[i][j], 0, 0, 0);
                acc[i][j] = __builtin_amdgcn_mfma_f32_16x16x32_bf16(af[i], bl[j], acc[i][j], 0, 0, 0);
            }
        }
        __syncthreads();
    }

    float bcol[4];
#pragma unroll
    for (int j = 0; j < 4; j++) bcol[j] = bias[bn + wn + j * 16 + lr];

    const int lq = (l >> 4) * 4;
#pragma unroll
    for (int i = 0; i < 4; i++) {
#pragma unroll
        for (int r0 = 0; r0 < 4; r0++) {
            int row = bm + wm + i * 16 + lq + r0;
            if (row < M) {
#pragma unroll
                for (int j = 0; j < 4; j++) {
                    float v = acc[i][j][r0] + bcol[j];
                    if (RELU) v = fmaxf(v, 0.f);
                    C[(size_t)row * H + bn + wn + j * 16 + lr] = f2bf(v);
                }
            }
        }
    }
}

// ---------------- fused tail: mean-pool -> @W3+b3 -> mlp1 -> mlp2, one block per graph ----------------
__global__ __launch_bounds__(256) void pool_mlp(
        const u16* __restrict__ a3, const int* __restrict__ goff,
        const float* __restrict__ W3, const float* __restrict__ b3,
        const float* __restrict__ Wm1, const float* __restrict__ bm1,
        const float* __restrict__ Wm2, const float* __restrict__ bm2,
        float* __restrict__ out) {
    __shared__ float p[H];
    __shared__ float y[H];
    __shared__ float hid[NHID];
    int g = blockIdx.x, t = threadIdx.x;
    int beg = goff[g], end = goff[g + 1];
    float acc = 0.f;
    for (int i = beg; i < end; i++) acc += bf2f(a3[(size_t)i * H + t]);
    p[t] = acc / fmaxf((float)(end - beg), 1.f);
    __syncthreads();
    // y = p @ W3 + b3   (pool-before-transform; W3 fp32 row-major [256][256])
    {
        float a = b3[t];
        for (int k = 0; k < H; k++) a += p[k] * W3[(size_t)k * H + t];
        y[t] = a;
    }
    __syncthreads();
#pragma unroll
    for (int rep = 0; rep < 2; rep++) {
        int o = rep * 256 + t;
        float a = bm1[o];
        for (int k = 0; k < H; k++) a += y[k] * Wm1[(size_t)k * NHID + o];
        hid[o] = fmaxf(a, 0.f);
    }
    __syncthreads();
    float a = bm2[t];
    for (int k = 0; k < NHID; k++) a += hid[k] * Wm2[(size_t)k * NOUT + t];
    out[g * NOUT + t] = a;
}

// ---------------- launch ----------------
extern "C" void kernel_launch(void* const* d_in, const int* in_sizes, int n_in,
                              void* d_out, int out_size, void* d_ws, size_t ws_size,
                              hipStream_t stream) {
    const float* x   = (const float*)d_in[0];
    const int*   src = (const int*)d_in[1];
    const int*   dst = (const int*)d_in[2];
    const int*   bat = (const int*)d_in[3];
    const float* W1  = (const float*)d_in[4];  const float* b1  = (const float*)d_in[5];
    const float* W2  = (const float*)d_in[6];  const float* b2  = (const float*)d_in[7];
    const float* W3  = (const float*)d_in[8];  const float* b3  = (const float*)d_in[9];
    const float* Wm1 = (const float*)d_in[10]; const float* bm1 = (const float*)d_in[11];
    const float* Wm2 = (const float*)d_in[12]; const float* bm2 = (const float*)d_in[13];
    float* out = (float*)d_out;

    char* p = (char*)d_ws;
    auto carve = [&](size_t bytes) -> void* {
        void* r = (void*)p;
        p += (bytes + 511) & ~(size_t)511;
        return r;
    };
    u16*   x_bf    = (u16*)  carve((size_t)N_NODES * F_IN * 2);
    u16*   aggX    = (u16*)  carve((size_t)N_NODES * F_IN * 2);
    u16*   bufA    = (u16*)  carve((size_t)N_NODES * H * 2);   // h1, then h2
    u16*   bufB    = (u16*)  carve((size_t)N_NODES * H * 2);   // a2, then a3
    float* dinv    = (float*)carve((size_t)N_NODES * 4);
    int*   degc    = (int*)  carve((size_t)N_NODES * 4);
    int*   rowp    = (int*)  carve((size_t)(N_NODES + 1) * 4);
    int*   cur     = (int*)  carve((size_t)N_NODES * 4);
    int*   esrc    = (int*)  carve((size_t)N_EDGES * 4);
    int*   partial = (int*)  carve(4096);
    int*   goff    = (int*)  carve((size_t)(G_GR + 1) * 4);
    u16*   Wt1_hi  = (u16*)  carve((size_t)F_IN * H * 2);
    u16*   Wt1_lo  = (u16*)  carve((size_t)F_IN * H * 2);
    u16*   Wt2_hi  = (u16*)  carve((size_t)H * H * 2);
    u16*   Wt2_lo  = (u16*)  carve((size_t)H * H * 2);

    const int NB = (N_NODES + 255) / 256;
    const int EB = (N_EDGES + 255) / 256;

    hipMemsetAsync(degc, 0, (size_t)N_NODES * 4, stream);
    count_deg<<<EB, 256, 0, stream>>>(dst, degc);
    scan_partial<<<NB, 256, 0, stream>>>(degc, partial);
    scan_offsets<<<1, 512, 0, stream>>>(partial, NB, rowp);
    scan_final_dinv<<<NB, 256, 0, stream>>>(degc, partial, rowp, cur, dinv);

    // scatter (latency-bound, LDS-free) overlapped with x->bf16 and W transposes
    scatter_prep_fused<<<PREP2_BLKS, 256, 0, stream>>>(
        src, dst, cur, esrc, x, x_bf,
        W1, Wt1_hi, Wt1_lo, W2, Wt2_hi, Wt2_lo, bat, goff);

    dim3 ggrid((N_NODES + 127) / 128, 2);
    const int AGG_B = N_NODES / 4;

    // layer 1: aggregate-first (128-wide gather), then transform+bias+relu
    gcn_agg128<<<AGG_B, 256, 0, stream>>>(x_bf, rowp, esrc, dinv, aggX);
    gemm_bias<F_IN, true><<<ggrid, 256, 0, stream>>>(aggX, Wt1_hi, Wt1_lo, b1, bufA, N_NODES);
    // layer 2: aggregate-first, transform+bias+relu
    gcn_agg256<<<AGG_B, 256, 0, stream>>>(bufA, rowp, esrc, dinv, bufB);
    gemm_bias<H, true><<<ggrid, 256, 0, stream>>>(bufB, Wt2_hi, Wt2_lo, b2, bufA, N_NODES);
    // layer 3: aggregate only; W3+b3 folded into pooled domain (linearity)
    gcn_agg256<<<AGG_B, 256, 0, stream>>>(bufA, rowp, esrc, dinv, bufB);

    pool_mlp<<<G_GR, 256, 0, stream>>>(bufB, goff, W3, b3, Wm1, bm1, Wm2, bm2, out);
}